// Round 1
// baseline (64687.018 us; speedup 1.0000x reference)
//
#include <hip/hip_runtime.h>
#include <math.h>

// RITS-style RNN + late attention, fused persistent kernel.
// B=1024 batch rows, S=256 steps, N=64 features, H=256 hidden, DA=350, DR=30.
//
// Design:
//  - prep_kernel: per-step msum[t] = sum(masks[:,t,:]) + 1e-5 (input-only, so the
//    recurrence becomes fully batch-parallel), tr_sum, zero loss accumulators.
//  - rits_main: 256 workgroups x 512 threads; wg g owns batch rows 4g..4g+3 for the
//    whole sequence. h in LDS, c in registers. Attention is online-softmax fused:
//    per (row, h-dim) thread keeps O[30] in registers; M/L in LDS. No H_rnn storage.
//  - final_kernel: assembles scalar loss.
// Workspace floats: [0]=xl_acc [1]=y_acc [2]=tr_sum [16..16+256)=msum.

#define BB 1024
#define SS 256
#define NF 64
#define HD 256
#define DAA 350
#define DRR 30
#define G4 1024

__device__ __forceinline__ float dot4f(float4 a, float4 b) {
  return fmaf(a.x, b.x, fmaf(a.y, b.y, fmaf(a.z, b.z, a.w * b.w)));
}

__global__ __launch_bounds__(256) void prep_kernel(
    const float* __restrict__ masks, const float* __restrict__ is_train,
    float* __restrict__ ws)
{
  __shared__ float red[256];
  const int t = blockIdx.x;
  const int tid = threadIdx.x;
  float s = 0.f;
  for (int idx = tid; idx < BB * NF; idx += 256) {
    int b = idx >> 6, n = idx & 63;
    s += masks[(size_t)b * (SS * NF) + (size_t)t * NF + n];
  }
  red[tid] = s;
  __syncthreads();
  for (int off = 128; off > 0; off >>= 1) {
    if (tid < off) red[tid] += red[tid + off];
    __syncthreads();
  }
  if (tid == 0) ws[16 + t] = red[0] + 1e-5f;
  if (blockIdx.x == 0) {
    __syncthreads();
    float ts = 0.f;
    for (int idx = tid; idx < BB; idx += 256) ts += is_train[idx];
    red[tid] = ts;
    __syncthreads();
    for (int off = 128; off > 0; off >>= 1) {
      if (tid < off) red[tid] += red[tid + off];
      __syncthreads();
    }
    if (tid == 0) { ws[2] = red[0]; ws[0] = 0.f; ws[1] = 0.f; }
  }
}

__global__ __launch_bounds__(512, 2) void rits_main(
    const float* __restrict__ values, const float* __restrict__ masks_g,
    const float* __restrict__ deltas, const float* __restrict__ labels,
    const float* __restrict__ is_train,
    const float* __restrict__ td_h_W, const float* __restrict__ td_h_b,
    const float* __restrict__ td_x_W, const float* __restrict__ td_x_b,
    const float* __restrict__ hist_W, const float* __restrict__ hist_b,
    const float* __restrict__ feat_W, const float* __restrict__ feat_b,
    const float* __restrict__ comb_W, const float* __restrict__ comb_b,
    const float* __restrict__ W_ih, const float* __restrict__ b_ih,
    const float* __restrict__ W_hh, const float* __restrict__ b_hh,
    const float* __restrict__ Ws1_W, const float* __restrict__ Ws1_b,
    const float* __restrict__ Ws2_W, const float* __restrict__ Ws2_b,
    const float* __restrict__ out_W, const float* __restrict__ out_b,
    float* __restrict__ out, float* __restrict__ ws)
{
  __shared__ __align__(16) float sh_h[4][HD];
  __shared__ __align__(16) float sh_x[4][NF];
  __shared__ __align__(16) float sh_m[4][NF];
  __shared__ __align__(16) float sh_d[4][NF];
  __shared__ __align__(16) float sh_xc[4][NF];
  __shared__ __align__(16) float sh_cc[4][NF];
  __shared__ __align__(16) float sh_gx[4][NF];
  __shared__ __align__(16) float sh_xh[4][NF];
  __shared__ __align__(16) float sh_s1[4][352];  // also reused as reduce scratch
  __shared__ float sh_w[4][32];
  __shared__ float sh_scale[4][32];
  __shared__ float sh_M[4][32];
  __shared__ float sh_L[4][32];
  __shared__ __align__(16) float sh_bg[G4];
  __shared__ float sh_msum;

  const int tid = threadIdx.x;
  const int b0 = blockIdx.x * 4;
  // gate/h-dim item mapping: thread -> (row, jA) and (row, jB=jA+128); both items
  // share `row` so LDS reads are reused across 2 items x 4 gates (register blocking)
  const int row = tid >> 7;
  const int j = tid & 127;
  const int jA = j, jB = j + 128;
  // feature item mapping (tid<256): (row2, nn)
  const int row2 = tid >> 6;
  const int nn = tid & 63;

  for (int g = tid; g < G4; g += 512) sh_bg[g] = b_ih[g] + b_hh[g];
  sh_h[row][jA] = 0.f;
  sh_h[row][jB] = 0.f;
  if (tid < 128) {
    int rr = tid >> 5, q = tid & 31;
    sh_M[rr][q] = -1e30f;
    sh_L[rr][q] = 0.f;
  }

  // per-thread cached scalar weights (fixed roles across all steps)
  const float tdhbA = td_h_b[jA];
  const float tdhbB = td_h_b[jB];
  const float tdxw = td_x_W[nn * NF + nn];   // diagonal of td_x_W
  const float tdxb = td_x_b[nn];
  const float histb = hist_b[nn];
  const float featb = feat_b[nn];
  const float featd = feat_W[nn * NF + nn];  // diagonal to subtract (zero-diag)
  const float combb = comb_b[nn];

  float cA = 0.f, cB = 0.f;
  float OA[DRR], OBv[DRR];
  #pragma unroll
  for (int r = 0; r < DRR; ++r) { OA[r] = 0.f; OBv[r] = 0.f; }
  double lossAcc = 0.0;

  __syncthreads();

  for (int t = 0; t < SS; ++t) {
    // ---- phase 1: stage x, d (low half) and m (high half); msum
    if (tid < 256) {
      size_t g = (size_t)(b0 + row2) * (SS * NF) + (size_t)t * NF + nn;
      sh_x[row2][nn] = values[g];
      sh_d[row2][nn] = deltas[g];
    } else {
      int q = tid - 256;
      int rw = q >> 6, n2 = q & 63;
      size_t g = (size_t)(b0 + rw) * (SS * NF) + (size_t)t * NF + n2;
      sh_m[rw][n2] = masks_g[g];
    }
    if (tid == 0) sh_msum = ws[16 + t];
    __syncthreads(); // S1

    // ---- phase 2: gamma_h = exp(-relu(d @ td_h_W^T + b)); h *= gamma_h; gamma_x
    {
      const float4* d4 = (const float4*)&sh_d[row][0];
      const float4* wA = (const float4*)(td_h_W + jA * NF);
      const float4* wB = (const float4*)(td_h_W + jB * NF);
      float aA = 0.f, aB = 0.f;
      #pragma unroll
      for (int k = 0; k < 16; ++k) {
        float4 dv = d4[k];
        aA += dot4f(dv, wA[k]);
        aB += dot4f(dv, wB[k]);
      }
      sh_h[row][jA] *= expf(-fmaxf(aA + tdhbA, 0.f));
      sh_h[row][jB] *= expf(-fmaxf(aB + tdhbB, 0.f));
    }
    if (tid < 256) {
      float v = sh_d[row2][nn] * tdxw + tdxb;  // diag(td_x_W) only
      sh_gx[row2][nn] = expf(-fmaxf(v, 0.f));
    }
    __syncthreads(); // S2

    // ---- phase 3: x_h = h_dec @ hist_W^T + b; x_c; loss term 1
    float lterm = 0.f;
    if (tid < 256) {
      const float4* h4 = (const float4*)&sh_h[row2][0];
      const float4* w4 = (const float4*)(hist_W + nn * HD);
      float a = 0.f;
      #pragma unroll 8
      for (int k = 0; k < 64; ++k) a += dot4f(h4[k], w4[k]);
      float xh = a + histb;
      sh_xh[row2][nn] = xh;
      float m = sh_m[row2][nn], x = sh_x[row2][nn];
      sh_xc[row2][nn] = m * x + (1.f - m) * xh;
      lterm = fabsf(x - xh) * m;
    }
    __syncthreads(); // S3

    // ---- phase 4: z_h (zero-diag feat), alpha, c_h, c_c (imputation), loss 2/3
    if (tid < 256) {
      const float4* xc4 = (const float4*)&sh_xc[row2][0];
      const float4* gx4 = (const float4*)&sh_gx[row2][0];
      const float4* mm4 = (const float4*)&sh_m[row2][0];
      const float4* fW  = (const float4*)(feat_W + nn * NF);
      const float4* cW0 = (const float4*)(comb_W + nn * 2 * NF);
      const float4* cW1 = (const float4*)(comb_W + nn * 2 * NF + NF);
      float az = 0.f, aa = 0.f;
      #pragma unroll
      for (int k = 0; k < 16; ++k) {
        az += dot4f(xc4[k], fW[k]);
        aa += dot4f(gx4[k], cW0[k]);
        aa += dot4f(mm4[k], cW1[k]);
      }
      float xcn = sh_xc[row2][nn];
      float zh = az - xcn * featd + featb;        // zero-diagonal correction
      float alpha = aa + combb;                   // raw linear (no sigmoid) per ref
      float xh = sh_xh[row2][nn];
      float chv = alpha * zh + (1.f - alpha) * xh;
      float m = sh_m[row2][nn], x = sh_x[row2][nn];
      float ccv = m * x + (1.f - m) * chv;
      sh_cc[row2][nn] = ccv;
      out[1 + BB + ((size_t)(b0 + row2) * SS + t) * NF + nn] = ccv;
      float lsum = lterm + (fabsf(x - zh) + fabsf(x - chv)) * m;
      lossAcc += (double)(lsum / sh_msum);
    }
    __syncthreads(); // S4

    // ---- phase 5: gates = [c_c, m] @ W_ih^T + h_dec @ W_hh^T + biases; LSTM
    float hnA, hnB;
    {
      float gA[4], gB[4];
      #pragma unroll
      for (int q = 0; q < 4; ++q) {
        gA[q] = sh_bg[q * 256 + jA];
        gB[q] = sh_bg[q * 256 + jB];
      }
      const float4* cc4 = (const float4*)&sh_cc[row][0];
      const float4* mm4 = (const float4*)&sh_m[row][0];
      const float4* hh4 = (const float4*)&sh_h[row][0];
      #pragma unroll
      for (int q = 0; q < 4; ++q) {  // q: i,f,g,o (torch order)
        const float4* wiA = (const float4*)(W_ih + (size_t)(q * 256 + jA) * 2 * NF);
        const float4* wiB = (const float4*)(W_ih + (size_t)(q * 256 + jB) * 2 * NF);
        float accA = 0.f, accB = 0.f;
        #pragma unroll 4
        for (int k = 0; k < 16; ++k) {
          float4 v = cc4[k];
          accA += dot4f(v, wiA[k]);
          accB += dot4f(v, wiB[k]);
        }
        #pragma unroll 4
        for (int k = 0; k < 16; ++k) {
          float4 v = mm4[k];
          accA += dot4f(v, wiA[16 + k]);
          accB += dot4f(v, wiB[16 + k]);
        }
        const float4* whA = (const float4*)(W_hh + (size_t)(q * 256 + jA) * HD);
        const float4* whB = (const float4*)(W_hh + (size_t)(q * 256 + jB) * HD);
        #pragma unroll 4
        for (int k = 0; k < 64; ++k) {
          float4 v = hh4[k];
          accA += dot4f(v, whA[k]);
          accB += dot4f(v, whB[k]);
        }
        gA[q] += accA; gB[q] += accB;
      }
      float iA = 1.f / (1.f + expf(-gA[0]));
      float fA = 1.f / (1.f + expf(-gA[1]));
      float oA = 1.f / (1.f + expf(-gA[3]));
      cA = fA * cA + iA * tanhf(gA[2]);
      hnA = oA * tanhf(cA);
      float iB = 1.f / (1.f + expf(-gB[0]));
      float fB = 1.f / (1.f + expf(-gB[1]));
      float oB = 1.f / (1.f + expf(-gB[3]));
      cB = fB * cB + iB * tanhf(gB[2]);
      hnB = oB * tanhf(cB);
    }
    __syncthreads(); // S5: all reads of sh_h/sh_cc/sh_m complete
    sh_h[row][jA] = hnA;
    sh_h[row][jB] = hnB;
    __syncthreads(); // S6

    // ---- phase 6: s1 = tanh(h @ Ws1^T + b1)
    for (int it = tid; it < 4 * DAA; it += 512) {
      int rw = it / DAA;
      int a = it - rw * DAA;
      const float4* h4 = (const float4*)&sh_h[rw][0];
      const float4* w4 = (const float4*)(Ws1_W + (size_t)a * HD);
      float acc = 0.f;
      #pragma unroll 8
      for (int k = 0; k < 64; ++k) acc += dot4f(h4[k], w4[k]);
      sh_s1[rw][a] = tanhf(acc + Ws1_b[a]);
    }
    __syncthreads(); // S7

    // ---- phase 7: scores + online-softmax state update (M, L, scale, w)
    if (tid < 4 * DRR) {
      int rw = tid / DRR;
      int r = tid - rw * DRR;
      const float2* s2 = (const float2*)&sh_s1[rw][0];
      const float2* w2 = (const float2*)(Ws2_W + (size_t)r * DAA);  // 1400B rows: float2-aligned
      float acc = 0.f;
      #pragma unroll 5
      for (int k = 0; k < 175; ++k) {
        float2 a = s2[k], b = w2[k];
        acc = fmaf(a.x, b.x, fmaf(a.y, b.y, acc));
      }
      float sc = acc + Ws2_b[r];
      float Mo = sh_M[rw][r];
      float Mn = fmaxf(Mo, sc);
      float scl = expf(Mo - Mn);
      float w = expf(sc - Mn);
      sh_M[rw][r] = Mn;
      sh_L[rw][r] = sh_L[rw][r] * scl + w;
      sh_scale[rw][r] = scl;
      sh_w[rw][r] = w;
    }
    __syncthreads(); // S8

    // ---- phase 8: O[r] = O[r]*scale + w*h  (registers, LDS broadcast operands)
    #pragma unroll
    for (int r = 0; r < DRR; ++r) {
      float scl = sh_scale[row][r];
      float w = sh_w[row][r];
      OA[r]  = OA[r]  * scl + w * hnA;
      OBv[r] = OBv[r] * scl + w * hnB;
    }
  }

  // ---- finalize: y_h = out_W . (O/L) per row, bce, predictions, loss reduce
  float pA = 0.f, pB = 0.f;
  #pragma unroll
  for (int r = 0; r < DRR; ++r) {
    float invL = 1.f / sh_L[row][r];
    pA += out_W[r * HD + jA] * (OA[r]  * invL);
    pB += out_W[r * HD + jB] * (OBv[r] * invL);
  }
  float* sred = &sh_s1[0][0];
  __syncthreads();
  sred[row * 256 + jA] = pA;
  sred[row * 256 + jB] = pB;
  __syncthreads();
  if (tid < 4) {
    float acc = 0.f;
    for (int k = 0; k < 256; ++k) acc += sred[tid * 256 + k];
    float yh = acc + out_b[0];
    int b = b0 + tid;
    float lab = labels[b], tr = is_train[b];
    float bce = fmaxf(yh, 0.f) - yh * lab + log1pf(expf(-fabsf(yh)));
    atomicAdd(&ws[1], bce * tr);
    out[1 + b] = 1.f / (1.f + expf(-yh));
  }
  __syncthreads();
  sred[tid] = (float)lossAcc;
  __syncthreads();
  for (int off = 256; off > 0; off >>= 1) {
    if (tid < off) sred[tid] += sred[tid + off];
    __syncthreads();
  }
  if (tid == 0) atomicAdd(&ws[0], sred[0]);
}

__global__ void final_kernel(const float* __restrict__ ws, float* __restrict__ out) {
  if (threadIdx.x == 0 && blockIdx.x == 0) {
    out[0] = ws[0] / (float)SS + 0.1f * (ws[1] / (ws[2] + 1e-5f));
  }
}

extern "C" void kernel_launch(void* const* d_in, const int* in_sizes, int n_in,
                              void* d_out, int out_size, void* d_ws, size_t ws_size,
                              hipStream_t stream) {
  const float* values   = (const float*)d_in[0];
  const float* masks    = (const float*)d_in[1];
  const float* deltas   = (const float*)d_in[2];
  const float* labels   = (const float*)d_in[3];
  const float* is_train = (const float*)d_in[4];
  const float* td_h_W   = (const float*)d_in[5];
  const float* td_h_b   = (const float*)d_in[6];
  const float* td_x_W   = (const float*)d_in[7];
  const float* td_x_b   = (const float*)d_in[8];
  const float* hist_W   = (const float*)d_in[9];
  const float* hist_b   = (const float*)d_in[10];
  const float* feat_W   = (const float*)d_in[11];
  const float* feat_b   = (const float*)d_in[12];
  const float* comb_W   = (const float*)d_in[13];
  const float* comb_b   = (const float*)d_in[14];
  const float* W_ih     = (const float*)d_in[15];
  const float* b_ih     = (const float*)d_in[16];
  const float* W_hh     = (const float*)d_in[17];
  const float* b_hh     = (const float*)d_in[18];
  const float* Ws1_W    = (const float*)d_in[19];
  const float* Ws1_b    = (const float*)d_in[20];
  const float* Ws2_W    = (const float*)d_in[21];
  const float* Ws2_b    = (const float*)d_in[22];
  const float* out_W    = (const float*)d_in[23];
  const float* out_b    = (const float*)d_in[24];
  float* out = (float*)d_out;
  float* ws  = (float*)d_ws;

  prep_kernel<<<SS, 256, 0, stream>>>(masks, is_train, ws);
  rits_main<<<BB / 4, 512, 0, stream>>>(
      values, masks, deltas, labels, is_train,
      td_h_W, td_h_b, td_x_W, td_x_b, hist_W, hist_b, feat_W, feat_b,
      comb_W, comb_b, W_ih, b_ih, W_hh, b_hh,
      Ws1_W, Ws1_b, Ws2_W, Ws2_b, out_W, out_b, out, ws);
  final_kernel<<<1, 64, 0, stream>>>(ws, out);
}

// Round 2
// 15044.472 us; speedup vs baseline: 4.2997x; 4.2997x over previous
//
#include <hip/hip_runtime.h>
#include <hip/hip_bf16.h>
#include <math.h>

// RITS-style RNN + late attention, fused persistent kernel. Round 2:
//  - batch-amortized register blocking: each weight element loaded ONCE per wg
//    per step and applied to all 4 batch rows (activations via LDS broadcast).
//  - W_ih|W_hh fused + Ws1 converted to bf16 in d_ws with a lane-coalesced
//    swizzle [kc][row][8]: lane tid reads (kc*1024+tid) float4 = coalesced 1KB.
//  - gate pre-activations exchanged via LDS so per-(row,j) threads keep c state.
// ws layout: f32 ws[0]=xl ws[1]=y ws[2]=tr_sum ws[16..272)=msum;
//            byte 4096: bf16 Wc[48][1024][8]; then bf16 Ws1[32][352][8].

#define BB 1024
#define SS 256
#define NF 64
#define HD 256
#define DAA 350
#define DRR 30

#define WS_WC_OFS   4096
#define WS_WC_ELEMS (1024 * 384)
#define WS_WS1_OFS  (WS_WC_OFS + WS_WC_ELEMS * 2)
#define WS_WS1_ELEMS (352 * 256)

__device__ __forceinline__ float dot4f(float4 a, float4 b) {
  return fmaf(a.x, b.x, fmaf(a.y, b.y, fmaf(a.z, b.z, a.w * b.w)));
}

// unpack 8 bf16 (packed in a float4) to 8 f32: 2 VALU ops per pair
__device__ __forceinline__ void bf8_cvt(float4 w, float* f) {
  union { float4 v; unsigned u[4]; } uu; uu.v = w;
  #pragma unroll
  for (int i = 0; i < 4; ++i) {
    f[2 * i]     = __uint_as_float(uu.u[i] << 16);
    f[2 * i + 1] = __uint_as_float(uu.u[i] & 0xffff0000u);
  }
}

__global__ __launch_bounds__(256) void convert_weights(
    const float* __restrict__ W_ih, const float* __restrict__ W_hh,
    const float* __restrict__ Ws1_W, __hip_bfloat16* __restrict__ wc,
    __hip_bfloat16* __restrict__ ws1b)
{
  int idx = blockIdx.x * 256 + threadIdx.x;
  if (idx < WS_WC_ELEMS) {
    int kc = idx >> 13;            // / (1024*8)
    int g  = (idx >> 3) & 1023;
    int e  = idx & 7;
    int k  = kc * 8 + e;           // 0..383: [c_c(64)|m(64)|h(256)]
    float v = (k < 128) ? W_ih[g * 128 + k] : W_hh[g * 256 + (k - 128)];
    wc[idx] = __float2bfloat16(v);
  } else {
    int i2 = idx - WS_WC_ELEMS;
    if (i2 < WS_WS1_ELEMS) {
      int kc = i2 / 2816;          // 352*8
      int rem = i2 - kc * 2816;
      int a = rem >> 3;
      int e = rem & 7;
      float v = (a < DAA) ? Ws1_W[a * 256 + kc * 8 + e] : 0.f;
      ws1b[i2] = __float2bfloat16(v);
    }
  }
}

__global__ __launch_bounds__(256) void prep_kernel(
    const float* __restrict__ masks, const float* __restrict__ is_train,
    float* __restrict__ ws)
{
  __shared__ float red[256];
  const int t = blockIdx.x;
  const int tid = threadIdx.x;
  float s = 0.f;
  for (int idx = tid; idx < BB * NF; idx += 256) {
    int b = idx >> 6, n = idx & 63;
    s += masks[(size_t)b * (SS * NF) + (size_t)t * NF + n];
  }
  red[tid] = s;
  __syncthreads();
  for (int off = 128; off > 0; off >>= 1) {
    if (tid < off) red[tid] += red[tid + off];
    __syncthreads();
  }
  if (tid == 0) ws[16 + t] = red[0] + 1e-5f;
  if (blockIdx.x == 0) {
    __syncthreads();
    float ts = 0.f;
    for (int idx = tid; idx < BB; idx += 256) ts += is_train[idx];
    red[tid] = ts;
    __syncthreads();
    for (int off = 128; off > 0; off >>= 1) {
      if (tid < off) red[tid] += red[tid + off];
      __syncthreads();
    }
    if (tid == 0) { ws[2] = red[0]; ws[0] = 0.f; ws[1] = 0.f; }
  }
}

__global__ __launch_bounds__(512, 2) void rits_main(
    const float* __restrict__ values, const float* __restrict__ masks_g,
    const float* __restrict__ deltas, const float* __restrict__ labels,
    const float* __restrict__ is_train,
    const float* __restrict__ td_h_W, const float* __restrict__ td_h_b,
    const float* __restrict__ td_x_W, const float* __restrict__ td_x_b,
    const float* __restrict__ hist_W, const float* __restrict__ hist_b,
    const float* __restrict__ feat_W, const float* __restrict__ feat_b,
    const float* __restrict__ comb_W, const float* __restrict__ comb_b,
    const float* __restrict__ b_ih, const float* __restrict__ b_hh,
    const float* __restrict__ Ws1_b,
    const float* __restrict__ Ws2_W, const float* __restrict__ Ws2_b,
    const float* __restrict__ out_W, const float* __restrict__ out_b,
    float* __restrict__ out, float* __restrict__ ws)
{
  // sh_a[r] = [c_c(0:64) | m(64:128) | h(128:384)] — the fused gate-GEMM operand
  __shared__ __align__(16) float sh_a[4][384];
  __shared__ __align__(16) float sh_x[4][NF];
  __shared__ __align__(16) float sh_d[4][NF];
  __shared__ __align__(16) float sh_xc[4][NF];
  __shared__ __align__(16) float sh_gx[4][NF];
  __shared__ __align__(16) float sh_xh[4][NF];
  __shared__ __align__(16) float sh_gates[4][1024];
  __shared__ __align__(16) float sh_s1[4][352];
  __shared__ float sh_w[4][32];
  __shared__ float sh_scale[4][32];
  __shared__ float sh_M[4][32];
  __shared__ float sh_L[4][32];
  __shared__ float sh_msum;

  const int tid = threadIdx.x;
  const int b0 = blockIdx.x * 4;
  // LSTM-state / attention mapping: (row, jA) and (row, jB)
  const int row = tid >> 7;
  const int j = tid & 127;
  const int jA = j, jB = j + 128;
  // feature mapping (tid<256)
  const int row2 = tid >> 6;
  const int nn = tid & 63;
  // phase-2 mapping: h-dim j2 for row pair 2*rh, 2*rh+1
  const int j2 = tid & 255;
  const int rh = tid >> 8;

  const __hip_bfloat16* wc_b = (const __hip_bfloat16*)((const char*)ws + WS_WC_OFS);
  const float4* wp  = (const float4*)wc_b;
  const float4* wp1 = (const float4*)((const char*)ws + WS_WS1_OFS);

  // init LDS state
  sh_a[row][128 + jA] = 0.f;
  sh_a[row][128 + jB] = 0.f;
  if (tid < 128) {
    int rr = tid >> 5, q = tid & 31;
    sh_M[rr][q] = -1e30f;
    sh_L[rr][q] = 0.f;
  }

  // per-thread cached scalars (fixed roles across steps)
  const float tdhb  = td_h_b[j2];
  const float tdxw  = td_x_W[nn * NF + nn];   // diag(td_x_W)
  const float tdxb  = td_x_b[nn];
  const float histb = hist_b[nn];
  const float featb = feat_b[nn];
  const float featd = feat_W[nn * NF + nn];   // diagonal (zeroed in ref)
  const float combb = comb_b[nn];
  const float bg0 = b_ih[tid] + b_hh[tid];
  const float bg1 = b_ih[tid + 512] + b_hh[tid + 512];
  const float w1bias = (tid < DAA) ? Ws1_b[tid] : 0.f;

  float cA = 0.f, cB = 0.f;
  float OA[DRR], OBv[DRR];
  #pragma unroll
  for (int r = 0; r < DRR; ++r) { OA[r] = 0.f; OBv[r] = 0.f; }
  double lossAcc = 0.0;

  __syncthreads();

  for (int t = 0; t < SS; ++t) {
    // ---- phase 1: stage x,d (low half) and m (high half, into sh_a m-region)
    if (tid < 256) {
      size_t g = (size_t)(b0 + row2) * (SS * NF) + (size_t)t * NF + nn;
      sh_x[row2][nn] = values[g];
      sh_d[row2][nn] = deltas[g];
    } else {
      int q = tid - 256;
      int rw = q >> 6, n2 = q & 63;
      size_t g = (size_t)(b0 + rw) * (SS * NF) + (size_t)t * NF + n2;
      sh_a[rw][64 + n2] = masks_g[g];
    }
    if (tid == 0) sh_msum = ws[16 + t];
    __syncthreads(); // S1

    // ---- phase 2: h *= gamma_h. Thread: dim j2 for 2 rows (weight loaded once)
    {
      const float4* wA = (const float4*)(td_h_W + j2 * NF);
      const float4* d0 = (const float4*)&sh_d[2 * rh][0];
      const float4* d1 = (const float4*)&sh_d[2 * rh + 1][0];
      float a0 = 0.f, a1 = 0.f;
      #pragma unroll
      for (int k = 0; k < 16; ++k) {
        float4 w = wA[k];
        a0 += dot4f(d0[k], w);
        a1 += dot4f(d1[k], w);
      }
      sh_a[2 * rh][128 + j2]     *= expf(-fmaxf(a0 + tdhb, 0.f));
      sh_a[2 * rh + 1][128 + j2] *= expf(-fmaxf(a1 + tdhb, 0.f));
    }
    if (tid < 256) {
      float v = sh_d[row2][nn] * tdxw + tdxb;  // diag only
      sh_gx[row2][nn] = expf(-fmaxf(v, 0.f));
    }
    __syncthreads(); // S2

    // ---- phase 3: x_h = h_dec @ hist_W^T + b; x_c; loss term 1
    float lterm = 0.f;
    if (tid < 256) {
      const float4* h4 = (const float4*)&sh_a[row2][128];
      const float4* w4 = (const float4*)(hist_W + nn * HD);
      float a = 0.f;
      #pragma unroll 8
      for (int k = 0; k < 64; ++k) a += dot4f(h4[k], w4[k]);
      float xh = a + histb;
      sh_xh[row2][nn] = xh;
      float m = sh_a[row2][64 + nn], x = sh_x[row2][nn];
      sh_xc[row2][nn] = m * x + (1.f - m) * xh;
      lterm = fabsf(x - xh) * m;
    }
    __syncthreads(); // S3

    // ---- phase 4: z_h (zero-diag), alpha, c_h, c_c into sh_a; loss 2/3
    if (tid < 256) {
      const float4* xc4 = (const float4*)&sh_xc[row2][0];
      const float4* gx4 = (const float4*)&sh_gx[row2][0];
      const float4* mm4 = (const float4*)&sh_a[row2][64];
      const float4* fW  = (const float4*)(feat_W + nn * NF);
      const float4* cW0 = (const float4*)(comb_W + nn * 2 * NF);
      const float4* cW1 = (const float4*)(comb_W + nn * 2 * NF + NF);
      float az = 0.f, aa = 0.f;
      #pragma unroll
      for (int k = 0; k < 16; ++k) {
        az += dot4f(xc4[k], fW[k]);
        aa += dot4f(gx4[k], cW0[k]);
        aa += dot4f(mm4[k], cW1[k]);
      }
      float xcn = sh_xc[row2][nn];
      float zh = az - xcn * featd + featb;
      float alpha = aa + combb;
      float xh = sh_xh[row2][nn];
      float chv = alpha * zh + (1.f - alpha) * xh;
      float m = sh_a[row2][64 + nn], x = sh_x[row2][nn];
      float ccv = m * x + (1.f - m) * chv;
      sh_a[row2][nn] = ccv;
      out[1 + BB + ((size_t)(b0 + row2) * SS + t) * NF + nn] = ccv;
      float lsum = lterm + (fabsf(x - zh) + fabsf(x - chv)) * m;
      lossAcc += (double)(lsum / sh_msum);
    }
    __syncthreads(); // S4

    // ---- phase 5: gates. Thread owns weight rows g0=tid, g1=tid+512 (coalesced
    // bf16 swizzle), applies each to ALL 4 batch rows (LDS broadcast operands).
    {
      float acc0[4] = {0.f, 0.f, 0.f, 0.f};
      float acc1[4] = {0.f, 0.f, 0.f, 0.f};
      #pragma unroll 2
      for (int kc = 0; kc < 48; ++kc) {
        float4 w0 = wp[kc * 1024 + tid];
        float4 w1 = wp[kc * 1024 + tid + 512];
        float f0[8], f1[8];
        bf8_cvt(w0, f0);
        bf8_cvt(w1, f1);
        #pragma unroll
        for (int r = 0; r < 4; ++r) {
          float4 a0 = *(const float4*)&sh_a[r][kc * 8];
          float4 a1 = *(const float4*)&sh_a[r][kc * 8 + 4];
          acc0[r] += f0[0]*a0.x + f0[1]*a0.y + f0[2]*a0.z + f0[3]*a0.w
                   + f0[4]*a1.x + f0[5]*a1.y + f0[6]*a1.z + f0[7]*a1.w;
          acc1[r] += f1[0]*a0.x + f1[1]*a0.y + f1[2]*a0.z + f1[3]*a0.w
                   + f1[4]*a1.x + f1[5]*a1.y + f1[6]*a1.z + f1[7]*a1.w;
        }
      }
      #pragma unroll
      for (int r = 0; r < 4; ++r) {
        sh_gates[r][tid]       = acc0[r] + bg0;
        sh_gates[r][tid + 512] = acc1[r] + bg1;
      }
    }
    __syncthreads(); // S5

    // ---- LSTM state update per (row, jA/jB); write new h into sh_a
    float hnA, hnB;
    {
      float giA = sh_gates[row][jA];
      float gfA = sh_gates[row][256 + jA];
      float ggA = sh_gates[row][512 + jA];
      float goA = sh_gates[row][768 + jA];
      float iA = 1.f / (1.f + expf(-giA));
      float fA = 1.f / (1.f + expf(-gfA));
      float oA = 1.f / (1.f + expf(-goA));
      cA = fA * cA + iA * tanhf(ggA);
      hnA = oA * tanhf(cA);
      float giB = sh_gates[row][jB];
      float gfB = sh_gates[row][256 + jB];
      float ggB = sh_gates[row][512 + jB];
      float goB = sh_gates[row][768 + jB];
      float iB = 1.f / (1.f + expf(-giB));
      float fB = 1.f / (1.f + expf(-gfB));
      float oB = 1.f / (1.f + expf(-goB));
      cB = fB * cB + iB * tanhf(ggB);
      hnB = oB * tanhf(cB);
      sh_a[row][128 + jA] = hnA;
      sh_a[row][128 + jB] = hnB;
    }
    __syncthreads(); // S6

    // ---- phase 6: s1 = tanh(h @ Ws1^T + b1). Thread owns Ws1 row tid (<352),
    // applies to all 4 rows (coalesced bf16 swizzle + LDS broadcast)
    if (tid < 352) {
      float acc[4] = {0.f, 0.f, 0.f, 0.f};
      #pragma unroll 2
      for (int kc = 0; kc < 32; ++kc) {
        float4 w = wp1[kc * 352 + tid];
        float f[8];
        bf8_cvt(w, f);
        #pragma unroll
        for (int r = 0; r < 4; ++r) {
          float4 a0 = *(const float4*)&sh_a[r][128 + kc * 8];
          float4 a1 = *(const float4*)&sh_a[r][128 + kc * 8 + 4];
          acc[r] += f[0]*a0.x + f[1]*a0.y + f[2]*a0.z + f[3]*a0.w
                  + f[4]*a1.x + f[5]*a1.y + f[6]*a1.z + f[7]*a1.w;
        }
      }
      #pragma unroll
      for (int r = 0; r < 4; ++r) sh_s1[r][tid] = tanhf(acc[r] + w1bias);
    }
    __syncthreads(); // S7

    // ---- phase 7: scores + online-softmax state (M, L, scale, w)
    if (tid < 4 * DRR) {
      int rw = tid / DRR;
      int r = tid - rw * DRR;
      const float2* s2 = (const float2*)&sh_s1[rw][0];
      const float2* w2 = (const float2*)(Ws2_W + (size_t)r * DAA);
      float acc = 0.f;
      #pragma unroll 5
      for (int k = 0; k < 175; ++k) {
        float2 a = s2[k], b = w2[k];
        acc = fmaf(a.x, b.x, fmaf(a.y, b.y, acc));
      }
      float sc = acc + Ws2_b[r];
      float Mo = sh_M[rw][r];
      float Mn = fmaxf(Mo, sc);
      float scl = expf(Mo - Mn);
      float w = expf(sc - Mn);
      sh_M[rw][r] = Mn;
      sh_L[rw][r] = sh_L[rw][r] * scl + w;
      sh_scale[rw][r] = scl;
      sh_w[rw][r] = w;
    }
    __syncthreads(); // S8

    // ---- phase 8: O[r] = O[r]*scale + w*h (registers; LDS broadcast)
    #pragma unroll
    for (int r = 0; r < DRR; ++r) {
      float scl = sh_scale[row][r];
      float w = sh_w[row][r];
      OA[r]  = OA[r]  * scl + w * hnA;
      OBv[r] = OBv[r] * scl + w * hnB;
    }
  }

  // ---- finalize: y_h = out_W . (O/L), bce, predictions, loss reduce
  float pA = 0.f, pB = 0.f;
  #pragma unroll
  for (int r = 0; r < DRR; ++r) {
    float invL = 1.f / sh_L[row][r];
    pA += out_W[r * HD + jA] * (OA[r]  * invL);
    pB += out_W[r * HD + jB] * (OBv[r] * invL);
  }
  float* sred = &sh_s1[0][0];  // 1408 floats of scratch
  __syncthreads();
  sred[row * 256 + jA] = pA;
  sred[row * 256 + jB] = pB;
  __syncthreads();
  if (tid < 4) {
    float acc = 0.f;
    for (int k = 0; k < 256; ++k) acc += sred[tid * 256 + k];
    float yh = acc + out_b[0];
    int b = b0 + tid;
    float lab = labels[b], tr = is_train[b];
    float bce = fmaxf(yh, 0.f) - yh * lab + log1pf(expf(-fabsf(yh)));
    atomicAdd(&ws[1], bce * tr);
    out[1 + b] = 1.f / (1.f + expf(-yh));
  }
  __syncthreads();
  sred[tid] = (float)lossAcc;
  __syncthreads();
  for (int off = 256; off > 0; off >>= 1) {
    if (tid < off) sred[tid] += sred[tid + off];
    __syncthreads();
  }
  if (tid == 0) atomicAdd(&ws[0], sred[0]);
}

__global__ void final_kernel(const float* __restrict__ ws, float* __restrict__ out) {
  if (threadIdx.x == 0 && blockIdx.x == 0) {
    out[0] = ws[0] / (float)SS + 0.1f * (ws[1] / (ws[2] + 1e-5f));
  }
}

extern "C" void kernel_launch(void* const* d_in, const int* in_sizes, int n_in,
                              void* d_out, int out_size, void* d_ws, size_t ws_size,
                              hipStream_t stream) {
  const float* values   = (const float*)d_in[0];
  const float* masks    = (const float*)d_in[1];
  const float* deltas   = (const float*)d_in[2];
  const float* labels   = (const float*)d_in[3];
  const float* is_train = (const float*)d_in[4];
  const float* td_h_W   = (const float*)d_in[5];
  const float* td_h_b   = (const float*)d_in[6];
  const float* td_x_W   = (const float*)d_in[7];
  const float* td_x_b   = (const float*)d_in[8];
  const float* hist_W   = (const float*)d_in[9];
  const float* hist_b   = (const float*)d_in[10];
  const float* feat_W   = (const float*)d_in[11];
  const float* feat_b   = (const float*)d_in[12];
  const float* comb_W   = (const float*)d_in[13];
  const float* comb_b   = (const float*)d_in[14];
  const float* W_ih     = (const float*)d_in[15];
  const float* b_ih     = (const float*)d_in[16];
  const float* W_hh     = (const float*)d_in[17];
  const float* b_hh     = (const float*)d_in[18];
  const float* Ws1_W    = (const float*)d_in[19];
  const float* Ws1_b    = (const float*)d_in[20];
  const float* Ws2_W    = (const float*)d_in[21];
  const float* Ws2_b    = (const float*)d_in[22];
  const float* out_W    = (const float*)d_in[23];
  const float* out_b    = (const float*)d_in[24];
  float* out = (float*)d_out;
  float* ws  = (float*)d_ws;

  __hip_bfloat16* wc   = (__hip_bfloat16*)((char*)d_ws + WS_WC_OFS);
  __hip_bfloat16* ws1b = (__hip_bfloat16*)((char*)d_ws + WS_WS1_OFS);

  convert_weights<<<(WS_WC_ELEMS + WS_WS1_ELEMS + 255) / 256, 256, 0, stream>>>(
      W_ih, W_hh, Ws1_W, wc, ws1b);
  prep_kernel<<<SS, 256, 0, stream>>>(masks, is_train, ws);
  rits_main<<<BB / 4, 512, 0, stream>>>(
      values, masks, deltas, labels, is_train,
      td_h_W, td_h_b, td_x_W, td_x_b, hist_W, hist_b, feat_W, feat_b,
      comb_W, comb_b, b_ih, b_hh, Ws1_b,
      Ws2_W, Ws2_b, out_W, out_b, out, ws);
  final_kernel<<<1, 64, 0, stream>>>(ws, out);
}

// Round 3
// 6147.078 us; speedup vs baseline: 10.5232x; 2.4474x over previous
//
#include <hip/hip_runtime.h>
#include <hip/hip_bf16.h>
#include <math.h>

// RITS-style RNN + late attention, fused persistent kernel. Round 3:
//  - MFMA (16x16x32 bf16, M=4 real rows) for the four matmul-shaped phases:
//    td_h (gamma_h), hist (x_h), gates (W_ih|W_hh fused), Ws1 (attention s1).
//  - Weights pre-swizzled in d_ws into exact B-fragment order: lane L of frag
//    (nt,kt) holds B[k=kt*32+(L>>4)*8+j][n=nt*16+(L&15)] -> one coalesced
//    global_load_dwordx4 per frag.
//  - A-fragments from bf16 activation mirror sh_ab[16][392] (rows 4..15 zero,
//    row stride 784B -> 2-way bank aliasing = free on gfx950).
//  - C layout col=lane&15,row=quad*4+reg: quad-0 lanes hold the 4 real rows.
// ws layout: f32 ws[0]=xl ws[1]=y ws[2]=tr_sum ws[16..272)=msum; then bf16
// B-frag tensors at WS_B5/B6/B3/B2 (total ~1.01 MB).

#define BB 1024
#define SS 256
#define NF 64
#define HD 256
#define DAA 350
#define DRR 30

#define WS_B5_OFS 4096
#define WS_B5_ELEMS (64 * 12 * 64 * 8)   // gates: 64 n-tiles x 12 k-tiles
#define WS_B6_OFS (WS_B5_OFS + WS_B5_ELEMS * 2)
#define WS_B6_ELEMS (22 * 8 * 64 * 8)    // Ws1: 22 n-tiles x 8 k-tiles
#define WS_B3_OFS (WS_B6_OFS + WS_B6_ELEMS * 2)
#define WS_B3_ELEMS (4 * 8 * 64 * 8)     // hist: 4 n-tiles x 8 k-tiles
#define WS_B2_OFS (WS_B3_OFS + WS_B3_ELEMS * 2)
#define WS_B2_ELEMS (16 * 2 * 64 * 8)    // td_h: 16 n-tiles x 2 k-tiles
#define CW_TOTAL (WS_B5_ELEMS + WS_B6_ELEMS + WS_B3_ELEMS + WS_B2_ELEMS)

typedef __attribute__((ext_vector_type(8))) short bf16x8;
typedef __attribute__((ext_vector_type(4))) float f32x4;

__device__ __forceinline__ float dot4f(float4 a, float4 b) {
  return fmaf(a.x, b.x, fmaf(a.y, b.y, fmaf(a.z, b.z, a.w * b.w)));
}

__device__ __forceinline__ short f2bs(float v) {
  __hip_bfloat16 t = __float2bfloat16(v);
  return *reinterpret_cast<short*>(&t);
}

__global__ __launch_bounds__(256) void convert_weights(
    const float* __restrict__ W_ih, const float* __restrict__ W_hh,
    const float* __restrict__ Ws1_W, const float* __restrict__ hist_W,
    const float* __restrict__ td_h_W,
    short* __restrict__ b5, short* __restrict__ b6,
    short* __restrict__ b3, short* __restrict__ b2)
{
  int idx = blockIdx.x * 256 + threadIdx.x;
  if (idx < WS_B5_ELEMS) {
    int j = idx & 7; int e8 = idx >> 3; int lane = e8 & 63; int tile = e8 >> 6;
    int kt = tile % 12, nt = tile / 12;
    int g = nt * 16 + (lane & 15);
    int k = kt * 32 + (lane >> 4) * 8 + j;  // [c_c(64)|m(64)|h(256)]
    float v = (k < 128) ? W_ih[g * 128 + k] : W_hh[g * 256 + (k - 128)];
    b5[idx] = f2bs(v);
  } else if (idx < WS_B5_ELEMS + WS_B6_ELEMS) {
    int i = idx - WS_B5_ELEMS;
    int j = i & 7; int e8 = i >> 3; int lane = e8 & 63; int tile = e8 >> 6;
    int kt = tile & 7, nt = tile >> 3;
    int a = nt * 16 + (lane & 15);
    int k = kt * 32 + (lane >> 4) * 8 + j;
    float v = (a < DAA) ? Ws1_W[a * 256 + k] : 0.f;
    b6[i] = f2bs(v);
  } else if (idx < WS_B5_ELEMS + WS_B6_ELEMS + WS_B3_ELEMS) {
    int i = idx - WS_B5_ELEMS - WS_B6_ELEMS;
    int j = i & 7; int e8 = i >> 3; int lane = e8 & 63; int tile = e8 >> 6;
    int kt = tile & 7, nt = tile >> 3;
    int n = nt * 16 + (lane & 15);
    int k = kt * 32 + (lane >> 4) * 8 + j;
    b3[i] = f2bs(hist_W[n * 256 + k]);
  } else if (idx < CW_TOTAL) {
    int i = idx - WS_B5_ELEMS - WS_B6_ELEMS - WS_B3_ELEMS;
    int j = i & 7; int e8 = i >> 3; int lane = e8 & 63; int tile = e8 >> 6;
    int kt = tile & 1, nt = tile >> 1;
    int g = nt * 16 + (lane & 15);
    int k = kt * 32 + (lane >> 4) * 8 + j;
    b2[i] = f2bs(td_h_W[g * 64 + k]);
  }
}

__global__ __launch_bounds__(256) void prep_kernel(
    const float* __restrict__ masks, const float* __restrict__ is_train,
    float* __restrict__ ws)
{
  __shared__ float red[256];
  const int t = blockIdx.x;
  const int tid = threadIdx.x;
  float s = 0.f;
  for (int idx = tid; idx < BB * NF; idx += 256) {
    int b = idx >> 6, n = idx & 63;
    s += masks[(size_t)b * (SS * NF) + (size_t)t * NF + n];
  }
  red[tid] = s;
  __syncthreads();
  for (int off = 128; off > 0; off >>= 1) {
    if (tid < off) red[tid] += red[tid + off];
    __syncthreads();
  }
  if (tid == 0) ws[16 + t] = red[0] + 1e-5f;
  if (blockIdx.x == 0) {
    __syncthreads();
    float ts = 0.f;
    for (int idx = tid; idx < BB; idx += 256) ts += is_train[idx];
    red[tid] = ts;
    __syncthreads();
    for (int off = 128; off > 0; off >>= 1) {
      if (tid < off) red[tid] += red[tid + off];
      __syncthreads();
    }
    if (tid == 0) { ws[2] = red[0]; ws[0] = 0.f; ws[1] = 0.f; }
  }
}

__global__ __launch_bounds__(512, 2) void rits_main(
    const float* __restrict__ values, const float* __restrict__ masks_g,
    const float* __restrict__ deltas, const float* __restrict__ labels,
    const float* __restrict__ is_train,
    const float* __restrict__ td_h_b, const float* __restrict__ td_x_W,
    const float* __restrict__ td_x_b, const float* __restrict__ hist_b,
    const float* __restrict__ feat_W, const float* __restrict__ feat_b,
    const float* __restrict__ comb_W, const float* __restrict__ comb_b,
    const float* __restrict__ b_ih, const float* __restrict__ b_hh,
    const float* __restrict__ Ws1_b,
    const float* __restrict__ Ws2_W, const float* __restrict__ Ws2_b,
    const float* __restrict__ out_W, const float* __restrict__ out_b,
    float* __restrict__ out, float* __restrict__ ws)
{
  __shared__ __align__(16) float sh_a[4][384];   // f32: [unused|m|h]
  __shared__ __align__(16) short sh_ab[16][392]; // bf16 mirror [c_c|m|h], rows 4+ zero
  __shared__ __align__(16) short sh_db[16][72];  // bf16 d, rows 4+ zero
  __shared__ __align__(16) float sh_x[4][NF];
  __shared__ __align__(16) float sh_d[4][NF];
  __shared__ __align__(16) float sh_xc[4][NF];
  __shared__ __align__(16) float sh_gx[4][NF];
  __shared__ __align__(16) float sh_xh[4][NF];
  __shared__ __align__(16) float sh_gates[4][1024];
  __shared__ __align__(16) float sh_s1[4][352];
  __shared__ float sh_w[4][32];
  __shared__ float sh_scale[4][32];
  __shared__ float sh_M[4][32];
  __shared__ float sh_L[4][32];
  __shared__ float sh_msum;

  const int tid = threadIdx.x;
  const int b0 = blockIdx.x * 4;
  const int wv = tid >> 6;       // wave 0..7
  const int lane = tid & 63;
  const int lm = lane & 15;      // m/n within MFMA tile
  const int lq = lane >> 4;      // quad
  const int row = tid >> 7;      // LSTM/attention row
  const int j = tid & 127;
  const int jA = j, jB = j + 128;
  const int row2 = tid >> 6;     // feature-phase row (tid<256)
  const int nn = tid & 63;

  const bf16x8* b5 = (const bf16x8*)((const char*)ws + WS_B5_OFS);
  const bf16x8* b6 = (const bf16x8*)((const char*)ws + WS_B6_OFS);
  const bf16x8* b3 = (const bf16x8*)((const char*)ws + WS_B3_OFS);
  const bf16x8* b2 = (const bf16x8*)((const char*)ws + WS_B2_OFS);

  // ---- init LDS
  for (int i = tid; i < 16 * 392; i += 512) (&sh_ab[0][0])[i] = 0;
  for (int i = tid; i < 16 * 72; i += 512) (&sh_db[0][0])[i] = 0;
  for (int i = tid; i < 4 * 384; i += 512) (&sh_a[0][0])[i] = 0.f;
  if (tid < 128) {
    int rr = tid >> 5, q = tid & 31;
    sh_M[rr][q] = -1e30f;
    sh_L[rr][q] = 0.f;
  }

  // per-thread cached scalars
  const float tdxw  = td_x_W[nn * NF + nn];
  const float tdxb  = td_x_b[nn];
  const float featb = feat_b[nn];
  const float featd = feat_W[nn * NF + nn];
  const float combb = comb_b[nn];
  float bgA[4], bgB[4];
  #pragma unroll
  for (int q = 0; q < 4; ++q) {
    bgA[q] = b_ih[q * 256 + jA] + b_hh[q * 256 + jA];
    bgB[q] = b_ih[q * 256 + jB] + b_hh[q * 256 + jB];
  }

  float cA = 0.f, cB = 0.f;
  float OA[DRR], OBv[DRR];
  #pragma unroll
  for (int r = 0; r < DRR; ++r) { OA[r] = 0.f; OBv[r] = 0.f; }
  double lossAcc = 0.0;

  __syncthreads();

  for (int t = 0; t < SS; ++t) {
    // ---- stage x,d (+bf16 d) on low half; m (f32+bf16) on high half
    if (tid < 256) {
      size_t g = (size_t)(b0 + row2) * (SS * NF) + (size_t)t * NF + nn;
      float xv = values[g], dv = deltas[g];
      sh_x[row2][nn] = xv;
      sh_d[row2][nn] = dv;
      sh_db[row2][nn] = f2bs(dv);
    } else {
      int q = tid - 256;
      int rw = q >> 6, n2 = q & 63;
      size_t g = (size_t)(b0 + rw) * (SS * NF) + (size_t)t * NF + n2;
      float mv = masks_g[g];
      sh_a[rw][64 + n2] = mv;
      sh_ab[rw][64 + n2] = f2bs(mv);
    }
    if (tid == 0) sh_msum = ws[16 + t];
    __syncthreads(); // S1

    // ---- phase 2: gamma_h via MFMA (16 n-tiles over h); writers decay h.
    {
      bf16x8 dfr[2];
      #pragma unroll
      for (int kt = 0; kt < 2; ++kt)
        dfr[kt] = *(const bf16x8*)(&sh_db[lm][0] + kt * 32 + lq * 8);
      #pragma unroll
      for (int ntl = 0; ntl < 2; ++ntl) {
        int nt = wv * 2 + ntl;
        f32x4 acc = {0.f, 0.f, 0.f, 0.f};
        const bf16x8* bp = b2 + (size_t)(nt * 2) * 64 + lane;
        acc = __builtin_amdgcn_mfma_f32_16x16x32_bf16(dfr[0], bp[0], acc, 0, 0, 0);
        acc = __builtin_amdgcn_mfma_f32_16x16x32_bf16(dfr[1], bp[64], acc, 0, 0, 0);
        if (lq == 0) {
          int g = nt * 16 + lm;
          float bias = td_h_b[g];
          #pragma unroll
          for (int r = 0; r < 4; ++r) {
            float gam = expf(-fmaxf(acc[r] + bias, 0.f));
            float h = sh_a[r][128 + g] * gam;
            sh_a[r][128 + g] = h;
            sh_ab[r][128 + g] = f2bs(h);
          }
        }
      }
      if (tid < 256) {
        float v = sh_d[row2][nn] * tdxw + tdxb;  // diag only
        sh_gx[row2][nn] = expf(-fmaxf(v, 0.f));
      }
    }
    __syncthreads(); // S2

    // ---- phase 3: x_h = h @ hist_W^T + b via MFMA (waves 0-3, 1 tile each)
    if (wv < 4) {
      int nt = wv;
      f32x4 acc = {0.f, 0.f, 0.f, 0.f};
      const bf16x8* bp = b3 + (size_t)(nt * 8) * 64 + lane;
      #pragma unroll
      for (int kt = 0; kt < 8; ++kt) {
        bf16x8 a = *(const bf16x8*)(&sh_ab[lm][128] + kt * 32 + lq * 8);
        acc = __builtin_amdgcn_mfma_f32_16x16x32_bf16(a, bp[kt * 64], acc, 0, 0, 0);
      }
      if (lq == 0) {
        int n = nt * 16 + lm;
        float bias = hist_b[n];
        float lterm = 0.f;
        #pragma unroll
        for (int r = 0; r < 4; ++r) {
          float xh = acc[r] + bias;
          sh_xh[r][n] = xh;
          float m = sh_a[r][64 + n], x = sh_x[r][n];
          sh_xc[r][n] = m * x + (1.f - m) * xh;
          lterm += fabsf(x - xh) * m;
        }
        lossAcc += (double)(lterm / sh_msum);
      }
    }
    __syncthreads(); // S3

    // ---- phase 4: z_h (zero-diag feat), alpha, c_h, c_c (f32 VALU)
    if (tid < 256) {
      const float4* xc4 = (const float4*)&sh_xc[row2][0];
      const float4* gx4 = (const float4*)&sh_gx[row2][0];
      const float4* mm4 = (const float4*)&sh_a[row2][64];
      const float4* fW  = (const float4*)(feat_W + nn * NF);
      const float4* cW0 = (const float4*)(comb_W + nn * 2 * NF);
      const float4* cW1 = (const float4*)(comb_W + nn * 2 * NF + NF);
      float az = 0.f, aa = 0.f;
      #pragma unroll
      for (int k = 0; k < 16; ++k) {
        az += dot4f(xc4[k], fW[k]);
        aa += dot4f(gx4[k], cW0[k]);
        aa += dot4f(mm4[k], cW1[k]);
      }
      float xcn = sh_xc[row2][nn];
      float zh = az - xcn * featd + featb;
      float alpha = aa + combb;
      float xh = sh_xh[row2][nn];
      float chv = alpha * zh + (1.f - alpha) * xh;
      float m = sh_a[row2][64 + nn], x = sh_x[row2][nn];
      float ccv = m * x + (1.f - m) * chv;
      sh_ab[row2][nn] = f2bs(ccv);
      out[1 + BB + ((size_t)(b0 + row2) * SS + t) * NF + nn] = ccv;
      float lsum = (fabsf(x - zh) + fabsf(x - chv)) * m;
      lossAcc += (double)(lsum / sh_msum);
    }
    __syncthreads(); // S4

    // ---- phase 5: gates via MFMA. Wave wv owns n-tiles wv*8..wv*8+7.
    {
      bf16x8 afr[12];
      #pragma unroll
      for (int kt = 0; kt < 12; ++kt)
        afr[kt] = *(const bf16x8*)(&sh_ab[lm][0] + kt * 32 + lq * 8);
      #pragma unroll 2
      for (int ntl = 0; ntl < 8; ++ntl) {
        int nt = wv * 8 + ntl;
        f32x4 acc = {0.f, 0.f, 0.f, 0.f};
        const bf16x8* bp = b5 + (size_t)(nt * 12) * 64 + lane;
        #pragma unroll
        for (int kt = 0; kt < 12; ++kt)
          acc = __builtin_amdgcn_mfma_f32_16x16x32_bf16(afr[kt], bp[kt * 64], acc, 0, 0, 0);
        if (lq == 0) {
          int n = nt * 16 + lm;
          #pragma unroll
          for (int r = 0; r < 4; ++r) sh_gates[r][n] = acc[r];
        }
      }
    }
    __syncthreads(); // S5

    // ---- LSTM state update; write new h (f32 + bf16)
    float hnA, hnB;
    {
      float giA = sh_gates[row][jA] + bgA[0];
      float gfA = sh_gates[row][256 + jA] + bgA[1];
      float ggA = sh_gates[row][512 + jA] + bgA[2];
      float goA = sh_gates[row][768 + jA] + bgA[3];
      float iA = 1.f / (1.f + expf(-giA));
      float fA = 1.f / (1.f + expf(-gfA));
      float oA = 1.f / (1.f + expf(-goA));
      cA = fA * cA + iA * tanhf(ggA);
      hnA = oA * tanhf(cA);
      float giB = sh_gates[row][jB] + bgB[0];
      float gfB = sh_gates[row][256 + jB] + bgB[1];
      float ggB = sh_gates[row][512 + jB] + bgB[2];
      float goB = sh_gates[row][768 + jB] + bgB[3];
      float iB = 1.f / (1.f + expf(-giB));
      float fB = 1.f / (1.f + expf(-gfB));
      float oB = 1.f / (1.f + expf(-goB));
      cB = fB * cB + iB * tanhf(ggB);
      hnB = oB * tanhf(cB);
      sh_a[row][128 + jA] = hnA;
      sh_a[row][128 + jB] = hnB;
      sh_ab[row][128 + jA] = f2bs(hnA);
      sh_ab[row][128 + jB] = f2bs(hnB);
    }
    __syncthreads(); // S6

    // ---- phase 6: s1 = tanh(h @ Ws1^T + b1) via MFMA (22 tiles)
    {
      bf16x8 hfr[8];
      #pragma unroll
      for (int kt = 0; kt < 8; ++kt)
        hfr[kt] = *(const bf16x8*)(&sh_ab[lm][128] + kt * 32 + lq * 8);
      for (int nt = wv; nt < 22; nt += 8) {
        f32x4 acc = {0.f, 0.f, 0.f, 0.f};
        const bf16x8* bp = b6 + (size_t)(nt * 8) * 64 + lane;
        #pragma unroll
        for (int kt = 0; kt < 8; ++kt)
          acc = __builtin_amdgcn_mfma_f32_16x16x32_bf16(hfr[kt], bp[kt * 64], acc, 0, 0, 0);
        if (lq == 0) {
          int a = nt * 16 + lm;
          if (a < DAA) {
            float bias = Ws1_b[a];
            #pragma unroll
            for (int r = 0; r < 4; ++r) sh_s1[r][a] = tanhf(acc[r] + bias);
          }
        }
      }
    }
    __syncthreads(); // S7

    // ---- phase 7: scores + online-softmax state (M, L, scale, w)
    if (tid < 4 * DRR) {
      int rw = tid / DRR;
      int r = tid - rw * DRR;
      const float2* s2 = (const float2*)&sh_s1[rw][0];
      const float2* w2 = (const float2*)(Ws2_W + (size_t)r * DAA);
      float acc = 0.f;
      #pragma unroll 5
      for (int k = 0; k < 175; ++k) {
        float2 a = s2[k], b = w2[k];
        acc = fmaf(a.x, b.x, fmaf(a.y, b.y, acc));
      }
      float sc = acc + Ws2_b[r];
      float Mo = sh_M[rw][r];
      float Mn = fmaxf(Mo, sc);
      float scl = expf(Mo - Mn);
      float w = expf(sc - Mn);
      sh_M[rw][r] = Mn;
      sh_L[rw][r] = sh_L[rw][r] * scl + w;
      sh_scale[rw][r] = scl;
      sh_w[rw][r] = w;
    }
    __syncthreads(); // S8

    // ---- phase 8: O[r] = O[r]*scale + w*h (registers; LDS broadcast)
    #pragma unroll
    for (int r = 0; r < DRR; ++r) {
      float scl = sh_scale[row][r];
      float w = sh_w[row][r];
      OA[r]  = OA[r]  * scl + w * hnA;
      OBv[r] = OBv[r] * scl + w * hnB;
    }
  }

  // ---- finalize: y_h = out_W . (O/L), bce, predictions, loss reduce
  float pA = 0.f, pB = 0.f;
  #pragma unroll
  for (int r = 0; r < DRR; ++r) {
    float invL = 1.f / sh_L[row][r];
    pA += out_W[r * HD + jA] * (OA[r]  * invL);
    pB += out_W[r * HD + jB] * (OBv[r] * invL);
  }
  float* sred = &sh_s1[0][0];  // 1408 floats of scratch
  __syncthreads();
  sred[row * 256 + jA] = pA;
  sred[row * 256 + jB] = pB;
  __syncthreads();
  if (tid < 4) {
    float acc = 0.f;
    for (int k = 0; k < 256; ++k) acc += sred[tid * 256 + k];
    float yh = acc + out_b[0];
    int b = b0 + tid;
    float lab = labels[b], tr = is_train[b];
    float bce = fmaxf(yh, 0.f) - yh * lab + log1pf(expf(-fabsf(yh)));
    atomicAdd(&ws[1], bce * tr);
    out[1 + b] = 1.f / (1.f + expf(-yh));
  }
  __syncthreads();
  sred[tid] = (float)lossAcc;
  __syncthreads();
  for (int off = 256; off > 0; off >>= 1) {
    if (tid < off) sred[tid] += sred[tid + off];
    __syncthreads();
  }
  if (tid == 0) atomicAdd(&ws[0], sred[0]);
}

__global__ void final_kernel(const float* __restrict__ ws, float* __restrict__ out) {
  if (threadIdx.x == 0 && blockIdx.x == 0) {
    out[0] = ws[0] / (float)SS + 0.1f * (ws[1] / (ws[2] + 1e-5f));
  }
}

extern "C" void kernel_launch(void* const* d_in, const int* in_sizes, int n_in,
                              void* d_out, int out_size, void* d_ws, size_t ws_size,
                              hipStream_t stream) {
  const float* values   = (const float*)d_in[0];
  const float* masks    = (const float*)d_in[1];
  const float* deltas   = (const float*)d_in[2];
  const float* labels   = (const float*)d_in[3];
  const float* is_train = (const float*)d_in[4];
  const float* td_h_W   = (const float*)d_in[5];
  const float* td_h_b   = (const float*)d_in[6];
  const float* td_x_W   = (const float*)d_in[7];
  const float* td_x_b   = (const float*)d_in[8];
  const float* hist_W   = (const float*)d_in[9];
  const float* hist_b   = (const float*)d_in[10];
  const float* feat_W   = (const float*)d_in[11];
  const float* feat_b   = (const float*)d_in[12];
  const float* comb_W   = (const float*)d_in[13];
  const float* comb_b   = (const float*)d_in[14];
  const float* W_ih     = (const float*)d_in[15];
  const float* b_ih     = (const float*)d_in[16];
  const float* W_hh     = (const float*)d_in[17];
  const float* b_hh     = (const float*)d_in[18];
  const float* Ws1_W    = (const float*)d_in[19];
  const float* Ws1_b    = (const float*)d_in[20];
  const float* Ws2_W    = (const float*)d_in[21];
  const float* Ws2_b    = (const float*)d_in[22];
  const float* out_W    = (const float*)d_in[23];
  const float* out_b    = (const float*)d_in[24];
  float* out = (float*)d_out;
  float* ws  = (float*)d_ws;

  short* b5 = (short*)((char*)d_ws + WS_B5_OFS);
  short* b6 = (short*)((char*)d_ws + WS_B6_OFS);
  short* b3 = (short*)((char*)d_ws + WS_B3_OFS);
  short* b2 = (short*)((char*)d_ws + WS_B2_OFS);

  convert_weights<<<(CW_TOTAL + 255) / 256, 256, 0, stream>>>(
      W_ih, W_hh, Ws1_W, hist_W, td_h_W, b5, b6, b3, b2);
  prep_kernel<<<SS, 256, 0, stream>>>(masks, is_train, ws);
  rits_main<<<BB / 4, 512, 0, stream>>>(
      values, masks, deltas, labels, is_train,
      td_h_b, td_x_W, td_x_b, hist_b, feat_W, feat_b, comb_W, comb_b,
      b_ih, b_hh, Ws1_b, Ws2_W, Ws2_b, out_W, out_b, out, ws);
  final_kernel<<<1, 64, 0, stream>>>(ws, out);
}